// Round 10
// baseline (137.572 us; speedup 1.0000x reference)
//
#include <hip/hip_runtime.h>

typedef float f32x4 __attribute__((ext_vector_type(4)));

#define NB 16
#define NC 64
#define NH 128
#define NW 128

// Padded xsum buffer: [16][130][136] floats.
// Row r = p+1 for output row p (rows 0,129 are zero halo).
// Col c = q+4 for input col q (cols 0..3 left halo, col 3 = q=-1; col 132 = q=128; 133-135 unused).
#define PROWS 130
#define PCOLS 136
#define XVOL  (NB * PROWS * PCOLS)          // 282,880 floats
#define WOFF  XVOL                          // flipped wsum: 64*9 floats after xsum

// ---- Kernel A: zero padded xsum, compute channel-summed FLIPPED 3x3 weights ----
__global__ void prep_kernel(const float* __restrict__ wgt, float* __restrict__ ws) {
  int gid = blockIdx.x * 256 + threadIdx.x;
  if (gid < XVOL / 4) {
    ((f32x4*)ws)[gid] = (f32x4){0.f, 0.f, 0.f, 0.f};
  }
  if (gid < 64 * 9) {
    int o = gid / 9;
    int t = gid - o * 9;
    int r = t / 3;
    int s = t - r * 3;
    // store at tap (r,s) the channel-sum of the FLIPPED weight w[o, :, 2-r, 2-s]
    const float* wp = wgt + o * (NC * 9) + (2 - r) * 3 + (2 - s);
    float acc = 0.f;
    #pragma unroll
    for (int i = 0; i < NC; ++i) acc += wp[i * 9];
    ws[WOFF + o * 9 + t] = acc;
  }
}

// ---- Kernel B: xsum[b,p,q] = sum_c x[b,c,p,q], written into padded interior ----
__global__ __launch_bounds__(256) void reduce_kernel(const float* __restrict__ x,
                                                     float* __restrict__ ws) {
  int idx = blockIdx.x * 256 + threadIdx.x;  // 65,536 threads: (b, p, q/4)
  int b   = idx >> 12;                       // 4096 per batch
  int rem = idx & 4095;
  int p   = rem >> 5;                        // 32 float4-groups per row
  int q0  = (rem & 31) << 2;

  const float* xp = x + b * (NC * NH * NW) + p * NW + q0;
  f32x4 acc = {0.f, 0.f, 0.f, 0.f};
  #pragma unroll 8
  for (int c = 0; c < NC; ++c) {
    f32x4 v = *(const f32x4*)(xp + c * (NH * NW));
    acc += v;
  }
  *(f32x4*)&ws[(b * PROWS + p + 1) * PCOLS + 4 + q0] = acc;
}

// ---- Kernel C: y[b,o,p,q] = sum_{kh,kw} xsum_pad[b][p+kh][q+kw+3] * wf[kh*3+kw] + bias[o] ----
__global__ __launch_bounds__(256) void conv_kernel(const float* __restrict__ ws,
                                                   const float* __restrict__ bias,
                                                   float* __restrict__ out) {
  int bid = blockIdx.x;
  int b   = bid >> 9;          // 512 blocks per batch
  int o   = (bid >> 3) & 63;
  int blk = bid & 7;

  int t     = threadIdx.x;
  int row16 = t >> 4;
  int cg    = t & 15;
  int p     = blk * 16 + row16;
  int q0    = cg * 8;

  // uniform per block: flipped wsum taps + bias (compiler scalarizes)
  const float* wf = ws + WOFF + o * 9;
  float w0 = wf[0], w1 = wf[1], w2 = wf[2];
  float w3 = wf[3], w4 = wf[4], w5 = wf[5];
  float w6 = wf[6], w7 = wf[7], w8 = wf[8];
  float bb = bias[o];

  const float* xp = ws + (b * PROWS + p) * PCOLS + (q0 + 3);
  float r0[10], r1[10], r2[10];
  #pragma unroll
  for (int j = 0; j < 10; ++j) {
    r0[j] = xp[j];
    r1[j] = xp[PCOLS + j];
    r2[j] = xp[2 * PCOLS + j];
  }

  float y[8];
  #pragma unroll
  for (int j = 0; j < 8; ++j) {
    float acc = bb;
    acc += w0 * r0[j] + w1 * r0[j + 1] + w2 * r0[j + 2];
    acc += w3 * r1[j] + w4 * r1[j + 1] + w5 * r1[j + 2];
    acc += w6 * r2[j] + w7 * r2[j + 1] + w8 * r2[j + 2];
    y[j] = acc;
  }

  float* op = out + ((b * 64 + o) * NH + p) * NW + q0;
  *(f32x4*)op       = (f32x4){y[0], y[1], y[2], y[3]};
  *(f32x4*)(op + 4) = (f32x4){y[4], y[5], y[6], y[7]};
}

extern "C" void kernel_launch(void* const* d_in, const int* in_sizes, int n_in,
                              void* d_out, int out_size, void* d_ws, size_t ws_size,
                              hipStream_t stream) {
  const float* x    = (const float*)d_in[0];
  const float* wgt  = (const float*)d_in[1];
  const float* bias = (const float*)d_in[2];
  float* out = (float*)d_out;
  float* ws  = (float*)d_ws;
  (void)in_sizes; (void)n_in; (void)out_size; (void)ws_size;

  // A: zero padded xsum (70,720 float4) + flipped channel-summed weights
  prep_kernel<<<dim3((XVOL / 4 + 255) / 256), dim3(256), 0, stream>>>(wgt, ws);
  // B: channel reduction, 16*128*128/4 threads
  reduce_kernel<<<dim3(NB * NH * NW / 4 / 256), dim3(256), 0, stream>>>(x, ws);
  // C: 3x3 conv from L2-resident xsum, 16*64*8 blocks
  conv_kernel<<<dim3(NB * 64 * 8), dim3(256), 0, stream>>>(ws, bias, out);
}

// Round 13
// 131.156 us; speedup vs baseline: 1.0489x; 1.0489x over previous
//
#include <hip/hip_runtime.h>

typedef float f32x4 __attribute__((ext_vector_type(4)));

#define NB 16
#define NC 64
#define NH 128
#define NW 128

// Padded xsum buffer: [16][130][136] floats.
// Padded row pr = p+1 for input row p (rows 0,129 zero halo).
// Padded col c = q+4 for input col q (col 3 = q=-1 halo, col 132 = q=128 halo).
// Conv kernel for output (p,q0..) reads padded rows p..p+2, cols q0+3..q0+12.
#define PROWS 130
#define PCOLS 136
#define XVOL  (NB * PROWS * PCOLS)          // 282,880 floats
#define WOFF  XVOL                          // flipped wsum: 64*9 floats after xsum
#define NRED  (NB * NH * NW / 4 / 256)      // 256 reduce blocks

// ---- Kernel R: channel reduction + (2 extra blocks) wsum prep + halo zero ----
__global__ __launch_bounds__(256) void reduce_prep_kernel(
    const float* __restrict__ x, const float* __restrict__ wgt,
    float* __restrict__ ws) {
  __shared__ float red[64][9][4];  // wsum partials [o][tap][quarter]

  const int bid = blockIdx.x;
  const int t   = threadIdx.x;

  if (bid < NRED) {
    // xsum[b,p,q] = sum_c x[b,c,p,q] -> padded interior
    int idx = bid * 256 + t;
    int b   = idx >> 12;
    int rem = idx & 4095;
    int p   = rem >> 5;
    int q0  = (rem & 31) << 2;

    const float* xp = x + b * (NC * NH * NW) + p * NW + q0;
    f32x4 acc0 = {0.f, 0.f, 0.f, 0.f};
    f32x4 acc1 = {0.f, 0.f, 0.f, 0.f};
    #pragma unroll 8
    for (int c = 0; c < NC; c += 2) {
      acc0 += *(const f32x4*)(xp + c * (NH * NW));
      acc1 += *(const f32x4*)(xp + (c + 1) * (NH * NW));
    }
    f32x4 acc = acc0 + acc1;
    *(f32x4*)&ws[(b * PROWS + p + 1) * PCOLS + 4 + q0] = acc;
  } else if (bid == NRED) {
    // wsum[o][3r+s] = sum_i w[o,i,2-r,2-s]  (flip == tap 8-t9)
    int quarter = t & 3;
    int o       = t >> 2;
    const float* base = wgt + o * (NC * 9) + quarter * (16 * 9);
    float part[9] = {0.f, 0.f, 0.f, 0.f, 0.f, 0.f, 0.f, 0.f, 0.f};
    #pragma unroll
    for (int i = 0; i < 16; ++i) {
      #pragma unroll
      for (int t9 = 0; t9 < 9; ++t9) part[t9] += base[i * 9 + t9];
    }
    #pragma unroll
    for (int t9 = 0; t9 < 9; ++t9) red[o][t9][quarter] = part[t9];
    __syncthreads();
    for (int s = t; s < 64 * 9; s += 256) {
      int o2 = s / 9;
      int t9 = s - o2 * 9;
      float v = red[o2][t9][0] + red[o2][t9][1] + red[o2][t9][2] + red[o2][t9][3];
      ws[WOFF + o2 * 9 + (8 - t9)] = v;  // store at flipped tap position
    }
  } else {
    // halo zero: rows 0 & 129 (full width) + cols 3 & 132 (rows 1..128), all b
    for (int idx = t; idx < NB * 2 * PCOLS; idx += 256) {
      int b   = idx / (2 * PCOLS);
      int rem = idx - b * (2 * PCOLS);
      int rr  = (rem >= PCOLS) ? (PROWS - 1) : 0;
      int col = (rem >= PCOLS) ? (rem - PCOLS) : rem;
      ws[(b * PROWS + rr) * PCOLS + col] = 0.f;
    }
    for (int idx = t; idx < NB * NH * 2; idx += 256) {
      int b   = idx >> 8;
      int rem = idx & 255;
      int row = 1 + (rem >> 1);
      int col = (rem & 1) ? 132 : 3;
      ws[(b * PROWS + row) * PCOLS + col] = 0.f;
    }
  }
}

// ---- Kernel C: y[b,o,p,q] = sum_{kh,kw} xsum_pad[b][p+kh][q+kw+3]*wf[3kh+kw] + bias[o]
__global__ __launch_bounds__(256) void conv_kernel(const float* __restrict__ ws,
                                                   const float* __restrict__ bias,
                                                   float* __restrict__ out) {
  int bid = blockIdx.x;
  int b   = bid >> 9;          // 512 blocks per batch (batch-major for L2 reuse)
  int o   = (bid >> 3) & 63;
  int blk = bid & 7;

  int t     = threadIdx.x;
  int row16 = t >> 4;
  int cg    = t & 15;
  int p     = blk * 16 + row16;
  int q0    = cg * 8;

  const float* wf = ws + WOFF + o * 9;
  float w0 = wf[0], w1 = wf[1], w2 = wf[2];
  float w3 = wf[3], w4 = wf[4], w5 = wf[5];
  float w6 = wf[6], w7 = wf[7], w8 = wf[8];
  float bb = bias[o];

  // 12 aligned f32x4 loads cover padded cols [q0, q0+16) x rows p..p+2
  const float* bp = ws + (b * PROWS + p) * PCOLS + q0;
  f32x4 L0[4], L1[4], L2[4];
  #pragma unroll
  for (int k = 0; k < 4; ++k) {
    L0[k] = *(const f32x4*)(bp + 4 * k);
    L1[k] = *(const f32x4*)(bp + PCOLS + 4 * k);
    L2[k] = *(const f32x4*)(bp + 2 * PCOLS + 4 * k);
  }

  // elem j (0..15) of row r = Lr[j>>2][j&3]; need j = 3..12
#define E0(j) (L0[(j) >> 2][(j) & 3])
#define E1(j) (L1[(j) >> 2][(j) & 3])
#define E2(j) (L2[(j) >> 2][(j) & 3])
  float y[8];
  #pragma unroll
  for (int j = 0; j < 8; ++j) {
    float acc = bb;
    acc += w0 * E0(j + 3) + w1 * E0(j + 4) + w2 * E0(j + 5);
    acc += w3 * E1(j + 3) + w4 * E1(j + 4) + w5 * E1(j + 5);
    acc += w6 * E2(j + 3) + w7 * E2(j + 4) + w8 * E2(j + 5);
    y[j] = acc;
  }
#undef E0
#undef E1
#undef E2

  float* op = out + ((b * 64 + o) * NH + p) * NW + q0;
  *(f32x4*)op       = (f32x4){y[0], y[1], y[2], y[3]};
  *(f32x4*)(op + 4) = (f32x4){y[4], y[5], y[6], y[7]};
}

extern "C" void kernel_launch(void* const* d_in, const int* in_sizes, int n_in,
                              void* d_out, int out_size, void* d_ws, size_t ws_size,
                              hipStream_t stream) {
  const float* x    = (const float*)d_in[0];
  const float* wgt  = (const float*)d_in[1];
  const float* bias = (const float*)d_in[2];
  float* out = (float*)d_out;
  float* ws  = (float*)d_ws;
  (void)in_sizes; (void)n_in; (void)out_size; (void)ws_size;

  // R: channel reduction (256 blocks) + wsum (1 block) + halo zero (1 block)
  reduce_prep_kernel<<<dim3(NRED + 2), dim3(256), 0, stream>>>(x, wgt, ws);
  // C: 3x3 conv from L2-resident xsum, 16*64*8 blocks
  conv_kernel<<<dim3(NB * 64 * 8), dim3(256), 0, stream>>>(ws, bias, out);
}

// Round 14
// 120.145 us; speedup vs baseline: 1.1450x; 1.0916x over previous
//
#include <hip/hip_runtime.h>

typedef float f32x4 __attribute__((ext_vector_type(4)));

#define NB 16
#define NC 64
#define NH 128
#define NW 128
#define STRIPE 8
#define LROWS (STRIPE + 2)   // 10 input rows incl. halo
#define LCOLS 136            // col c = q+4, q in -1..128 -> c 3..132; 16B-aligned rows

// One block = (batch b, stripe of 8 output rows). Everything in LDS, no workspace.
__global__ __launch_bounds__(256) void fused_conv_kernel(
    const float* __restrict__ x, const float* __restrict__ wgt,
    const float* __restrict__ bias, float* __restrict__ out) {
  __shared__ float xs[LROWS][LCOLS];   // channel-summed input tile
  __shared__ float red[64][9][4];      // wsum partials [o][raw tap][quarter]
  __shared__ float wl[64][12];         // [o][0..8]=flipped wsum, [9]=bias

  const int t   = threadIdx.x;
  const int bid = blockIdx.x;
  const int b   = bid >> 4;
  const int R0  = (bid & 15) * STRIPE;

  // ---- Phase X: xs[lr][*] = sum_c x[b,c,R0-1+lr,*]  (HBM stream, 16 loads in flight)
  {
    const int lr = t >> 5;           // 0..7 (tasks 0..255); rows 8,9 done by t<64 below
    const int g  = t & 31;
    const int ir = R0 - 1 + lr;
    f32x4 a0 = {0,0,0,0}, a1 = {0,0,0,0}, a2 = {0,0,0,0}, a3 = {0,0,0,0};
    if (ir >= 0 && ir < NH) {
      const float* xp = x + (b * NC * NH + ir) * NW + g * 4;
      #pragma unroll 4
      for (int c = 0; c < NC; c += 4) {
        a0 += *(const f32x4*)(xp + (c + 0) * (NH * NW));
        a1 += *(const f32x4*)(xp + (c + 1) * (NH * NW));
        a2 += *(const f32x4*)(xp + (c + 2) * (NH * NW));
        a3 += *(const f32x4*)(xp + (c + 3) * (NH * NW));
      }
    }
    *(f32x4*)&xs[lr][4 + g * 4] = (a0 + a1) + (a2 + a3);

    if (t < 64) {                    // tasks 256..319: rows 8,9
      const int lr2 = 8 + (t >> 5);
      const int ir2 = R0 - 1 + lr2;
      f32x4 c0 = {0,0,0,0}, c1 = {0,0,0,0}, c2 = {0,0,0,0}, c3 = {0,0,0,0};
      if (ir2 >= 0 && ir2 < NH) {
        const float* xp = x + (b * NC * NH + ir2) * NW + g * 4;
        #pragma unroll 4
        for (int c = 0; c < NC; c += 4) {
          c0 += *(const f32x4*)(xp + (c + 0) * (NH * NW));
          c1 += *(const f32x4*)(xp + (c + 1) * (NH * NW));
          c2 += *(const f32x4*)(xp + (c + 2) * (NH * NW));
          c3 += *(const f32x4*)(xp + (c + 3) * (NH * NW));
        }
      }
      *(f32x4*)&xs[lr2][4 + g * 4] = (c0 + c1) + (c2 + c3);
    }
    if (t < 2 * LROWS) xs[t >> 1][(t & 1) ? 132 : 3] = 0.f;  // col halos q=-1,128
  }

  // ---- Phase W: per-block redundant wsum partials (L2-hot, overlaps other blocks' X)
  {
    const int o  = t >> 2;
    const int qr = t & 3;
    const float* wp = wgt + o * (NC * 9) + qr * (16 * 9);
    float part[9] = {0.f, 0.f, 0.f, 0.f, 0.f, 0.f, 0.f, 0.f, 0.f};
    #pragma unroll
    for (int i = 0; i < 16; ++i) {
      #pragma unroll
      for (int k = 0; k < 9; ++k) part[k] += wp[i * 9 + k];
    }
    #pragma unroll
    for (int k = 0; k < 9; ++k) red[o][k][qr] = part[k];
  }
  __syncthreads();

  // combine quarters; store at FLIPPED tap (raw t9 -> flipped 8-t9); append bias
  for (int s2 = t; s2 < 576; s2 += 256) {
    int o  = s2 / 9;
    int t9 = s2 - o * 9;
    wl[o][8 - t9] = red[o][t9][0] + red[o][t9][1] + red[o][t9][2] + red[o][t9][3];
  }
  if (t < 64) wl[t][9] = bias[t];
  __syncthreads();

  // ---- Phase C: thread = (row ro, col group g); all 64 couts; X-tile in registers
  {
    const int ro = t >> 5;           // 0..7
    const int g  = t & 31;
    const int q0 = g * 4;
    float X0[6], X1[6], X2[6];
    #pragma unroll
    for (int m = 0; m < 6; ++m) {
      X0[m] = xs[ro][q0 + 3 + m];
      X1[m] = xs[ro + 1][q0 + 3 + m];
      X2[m] = xs[ro + 2][q0 + 3 + m];
    }
    float* op = out + ((b * 64) * NH + R0 + ro) * NW + q0;
    for (int o = 0; o < 64; ++o) {
      f32x4 wa = *(const f32x4*)&wl[o][0];   // wf0..wf3
      f32x4 wb = *(const f32x4*)&wl[o][4];   // wf4..wf7
      f32x4 wc = *(const f32x4*)&wl[o][8];   // wf8, bias, pad, pad
      f32x4 y;
      #pragma unroll
      for (int jj = 0; jj < 4; ++jj) {
        float acc = wc[1];
        acc += wa[0] * X0[jj] + wa[1] * X0[jj + 1] + wa[2] * X0[jj + 2];
        acc += wa[3] * X1[jj] + wb[0] * X1[jj + 1] + wb[1] * X1[jj + 2];
        acc += wb[2] * X2[jj] + wb[3] * X2[jj + 1] + wc[0] * X2[jj + 2];
        y[jj] = acc;
      }
      *(f32x4*)(op + o * (NH * NW)) = y;
    }
  }
}

extern "C" void kernel_launch(void* const* d_in, const int* in_sizes, int n_in,
                              void* d_out, int out_size, void* d_ws, size_t ws_size,
                              hipStream_t stream) {
  const float* x    = (const float*)d_in[0];
  const float* wgt  = (const float*)d_in[1];
  const float* bias = (const float*)d_in[2];
  float* out = (float*)d_out;
  (void)in_sizes; (void)n_in; (void)out_size; (void)d_ws; (void)ws_size;

  // One dispatch: 16 batches x 16 row-stripes, 256 threads
  fused_conv_kernel<<<dim3(NB * (NH / STRIPE)), dim3(256), 0, stream>>>(x, wgt, bias, out);
}